// Round 6
// baseline (288.335 us; speedup 1.0000x reference)
//
#include <hip/hip_runtime.h>
#include <hip/hip_bf16.h>
#include <stdint.h>

#define D_MODEL 1024
#define NHEAD   16
#define DH      64

typedef __attribute__((ext_vector_type(8))) short bf16x8;
typedef __attribute__((ext_vector_type(4))) float f32x4;

__device__ __forceinline__ ushort f2bf(float f) {
    __hip_bfloat16 h = __float2bfloat16(f);
    return *reinterpret_cast<ushort*>(&h);
}

__device__ __forceinline__ void gload_lds16(const void* g, void* l) {
    __builtin_amdgcn_global_load_lds(
        (const __attribute__((address_space(1))) void*)g,
        (__attribute__((address_space(3))) void*)l, 16, 0, 0);
}

// Load 8 contiguous fp32, convert to bf16x8 in-register.
__device__ __forceinline__ bf16x8 load8f(const float* p) {
    const float4 a = *(const float4*)p;
    const float4 b = *(const float4*)(p + 4);
    bf16x8 r;
    r[0] = (short)f2bf(a.x); r[1] = (short)f2bf(a.y);
    r[2] = (short)f2bf(a.z); r[3] = (short)f2bf(a.w);
    r[4] = (short)f2bf(b.x); r[5] = (short)f2bf(b.y);
    r[6] = (short)f2bf(b.z); r[7] = (short)f2bf(b.w);
    return r;
}

// fp32 -> bf16 weight conversion: 4 matrices of 1M elements each.
__global__ __launch_bounds__(256) void cvt_w_kernel(
    const float* __restrict__ w0, const float* __restrict__ w1,
    const float* __restrict__ w2, const float* __restrict__ w3,
    ushort* __restrict__ out)
{
    const int g = blockIdx.x * 256 + threadIdx.x;   // group of 8 elems
    const int m = g >> 17;                          // 131072 groups / matrix
    const int off = (g & 131071) * 8;
    const float* src = (m == 0) ? w0 : (m == 1) ? w1 : (m == 2) ? w2 : w3;
    *(bf16x8*)(out + (size_t)m * 1048576 + off) = load8f(src + off);
}

// fp32 -> bf16 for Q/K/V inputs (one-shot; kills 8x redundant conversion).
__global__ __launch_bounds__(256) void cvt_x_kernel(
    const float* __restrict__ Q, const float* __restrict__ K,
    const float* __restrict__ V,
    ushort* __restrict__ Qb, ushort* __restrict__ Kb, ushort* __restrict__ Vb)
{
    const int z = blockIdx.z;
    const float* src = (z == 0) ? Q : (z == 1) ? K : V;
    ushort* dst = (z == 0) ? Qb : (z == 1) ? Kb : Vb;
    const int off = (blockIdx.x * 256 + threadIdx.x) * 8;
    *(bf16x8*)(dst + off) = load8f(src + off);
}

// ---- shared GEMM epilogue helpers ----
__device__ __forceinline__ void storeC(float*  C, size_t i, float v) { C[i] = v; }
__device__ __forceinline__ void storeC(ushort* C, size_t i, float v) { C[i] = (short)f2bf(v); }

__device__ __forceinline__ void xcd_swizzle(int& bx, int& by) {
    if (gridDim.x == 8 && (gridDim.y & 7) == 0) {
        const int fid   = by * 8 + bx;
        const int xcd   = fid & 7;
        const int local = fid >> 3;
        const int rpx   = gridDim.y >> 3;
        by = xcd * rpx + (local >> 3);
        bx = local & 7;
    }
}

// R6: counted-vmcnt double-buffered pipeline (T3 minimum + T4) for all-DMA
// bf16 GEMMs. Per K-step: stage NEXT tile (4 DMA loads NW=4 / 2 loads NW=8),
// s_waitcnt vmcnt(4|2) — waits only step-t's loads, next step's stay IN
// FLIGHT across the barrier (the AITER pattern; never drain to 0 in-loop) —
// raw s_barrier, fragment ds_read + MFMA, lgkmcnt(0) (reads captured before
// other waves may overwrite), raw s_barrier. R1's version of this failed
// because __syncthreads() compiles to a full vmcnt(0) drain — the documented
// m97-ceiling mechanism; raw barriers + counted waits are the fix.
template<int NW, typename TOUT>
__device__ __forceinline__ void gemm_pipe(
    const ushort* __restrict__ X,
    const ushort* __restrict__ Wb,
    const float* __restrict__ Bias,
    TOUT* __restrict__ C,
    int M, int N, int K, float scale,
    short* As, short* Bs)          // each 2 bufs x 4096 shorts
{
    const int tid  = threadIdx.x;
    const int w    = tid >> 6;
    const int lane = tid & 63;
    const int quad = lane >> 4;
    const int l15  = lane & 15;
    const int wr   = (NW == 4) ? (w >> 1) : (w >> 2);
    const int wc   = (NW == 4) ? (w & 1)  : (w & 3);
    const int NJ   = (NW == 4) ? 4 : 2;
    const int colw = (NW == 4) ? 64 : 32;
    const int CH   = 8 / NW;               // 1KB chunks per wave per matrix

    int bx = blockIdx.x, by = blockIdx.y;
    xcd_swizzle(bx, by);
    const int m0 = by * 128;
    const int n0 = bx * 128;

    const int rin  = lane >> 2;            // row within chunk (0..15)
    const int col8 = (lane & 3) * 8;

    f32x4 acc[4][4] = {};

    auto stage = [&](int buf, int k0) {
        #pragma unroll
        for (int c = 0; c < CH; ++c) {
            int chunk = w * CH + c;
            int row   = chunk * 16 + rin;
            gload_lds16(Wb + (size_t)(n0 + row) * K + k0 + col8,
                        &Bs[buf * 4096 + chunk * 512]);
        }
        #pragma unroll
        for (int c = 0; c < CH; ++c) {
            int chunk = w * CH + c;
            int row   = chunk * 16 + rin;
            gload_lds16(X + (size_t)(m0 + row) * K + k0 + col8,
                        &As[buf * 4096 + chunk * 512]);
        }
    };

    const int NT = K >> 5;
    stage(0, 0);
    int buf = 0;
    for (int t = 0; t < NT; ++t) {
        if (t + 1 < NT) {
            stage(buf ^ 1, (t + 1) << 5);
            // wait step-t's loads only; step-(t+1)'s stay in flight
            if constexpr (NW == 4) asm volatile("s_waitcnt vmcnt(4)" ::: "memory");
            else                   asm volatile("s_waitcnt vmcnt(2)" ::: "memory");
        } else {
            asm volatile("s_waitcnt vmcnt(0)" ::: "memory");
        }
        __builtin_amdgcn_s_barrier();
        asm volatile("" ::: "memory");

        bf16x8 af[4], bfr[4];
        #pragma unroll
        for (int i = 0; i < 4; ++i)
            af[i] = *(const bf16x8*)&As[buf * 4096 + (wr * 64 + i * 16 + l15) * 32 + quad * 8];
        #pragma unroll
        for (int j = 0; j < NJ; ++j)
            bfr[j] = *(const bf16x8*)&Bs[buf * 4096 + (wc * colw + j * 16 + l15) * 32 + quad * 8];
        #pragma unroll
        for (int i = 0; i < 4; ++i)
            #pragma unroll
            for (int j = 0; j < NJ; ++j)
                acc[i][j] = __builtin_amdgcn_mfma_f32_16x16x32_bf16(af[i], bfr[j], acc[i][j], 0, 0, 0);

        // all our ds_reads retired (data in regs) before signalling peers
        asm volatile("s_waitcnt lgkmcnt(0)" ::: "memory");
        __builtin_amdgcn_s_barrier();
        buf ^= 1;
    }

    float bias[4];
    #pragma unroll
    for (int j = 0; j < NJ; ++j)
        bias[j] = Bias[n0 + wc * colw + j * 16 + l15];

    #pragma unroll
    for (int i = 0; i < 4; ++i) {
        int row = m0 + wr * 64 + i * 16 + quad * 4;
        #pragma unroll
        for (int j = 0; j < NJ; ++j) {
            int col = n0 + wc * colw + j * 16 + l15;
            #pragma unroll
            for (int r = 0; r < 4; ++r)
                storeC(C, (size_t)(row + r) * N + col, (acc[i][j][r] + bias[j]) * scale);
        }
    }
}

// Fallback core (fp32 A, in-loop conversion) — R3-proven, __syncthreads form.
__device__ __forceinline__ void gemm_core_f32(
    const float* __restrict__ X,
    const ushort* __restrict__ Wb,
    const float* __restrict__ Bias,
    ushort* __restrict__ C,
    int M, int N, int K, float scale,
    short* As, short* Bs)
{
    const int tid  = threadIdx.x;
    const int w    = tid >> 6;
    const int lane = tid & 63;
    const int quad = lane >> 4;
    const int l15  = lane & 15;
    const int wr   = w >> 1, wc = w & 1;

    int bx = blockIdx.x, by = blockIdx.y;
    xcd_swizzle(bx, by);
    const int m0 = by * 128;
    const int n0 = bx * 128;

    f32x4 acc[4][4] = {};

    for (int k0 = 0; k0 < K; k0 += 32) {
        __syncthreads();
        #pragma unroll
        for (int c = 0; c < 2; ++c) {
            int chunk = w * 2 + c;
            int row   = chunk * 16 + (lane >> 2);
            gload_lds16(Wb + (size_t)(n0 + row) * K + k0 + (lane & 3) * 8,
                        &Bs[chunk * 512]);
        }
        #pragma unroll
        for (int c = 0; c < 2; ++c) {
            int idx = c * 256 + tid;
            int row = idx >> 2;
            int col = (idx & 3) * 8;
            *(bf16x8*)&As[row * 32 + col] =
                load8f(X + (size_t)(m0 + row) * K + k0 + col);
        }
        __syncthreads();

        bf16x8 af[4], bfr[4];
        #pragma unroll
        for (int i = 0; i < 4; ++i)
            af[i] = *(const bf16x8*)&As[(wr * 64 + i * 16 + l15) * 32 + quad * 8];
        #pragma unroll
        for (int j = 0; j < 4; ++j)
            bfr[j] = *(const bf16x8*)&Bs[(wc * 64 + j * 16 + l15) * 32 + quad * 8];
        #pragma unroll
        for (int i = 0; i < 4; ++i)
            #pragma unroll
            for (int j = 0; j < 4; ++j)
                acc[i][j] = __builtin_amdgcn_mfma_f32_16x16x32_bf16(af[i], bfr[j], acc[i][j], 0, 0, 0);
    }

    float bias[4];
    #pragma unroll
    for (int j = 0; j < 4; ++j)
        bias[j] = Bias[n0 + wc * 64 + j * 16 + l15];

    #pragma unroll
    for (int i = 0; i < 4; ++i) {
        int row = m0 + wr * 64 + i * 16 + quad * 4;
        #pragma unroll
        for (int j = 0; j < 4; ++j) {
            int col = n0 + wc * 64 + j * 16 + l15;
            #pragma unroll
            for (int r = 0; r < 4; ++r)
                storeC(C, (size_t)(row + r) * N + col, (acc[i][j][r] + bias[j]) * scale);
        }
    }
}

__global__ __launch_bounds__(256) void qkv_proj_f32_kernel(
    const float* __restrict__ Qin, const float* __restrict__ Kin,
    const float* __restrict__ Vin,
    const ushort* __restrict__ Wb,
    const float* __restrict__ Bq, const float* __restrict__ Bk,
    const float* __restrict__ Bv,
    ushort* qo, ushort* ko, ushort* vo, int L)
{
    __shared__ short As[4096];
    __shared__ short Bs[4096];
    const int z = blockIdx.z;
    const float *X, *B; ushort* C;
    float scale = 1.0f;
    if (z == 0)      { X = Qin; B = Bq; C = qo; scale = 0.125f * 1.44269504088896f; }
    else if (z == 1) { X = Kin; B = Bk; C = ko; }
    else             { X = Vin; B = Bv; C = vo; }
    gemm_core_f32(X, Wb + (size_t)z * 1048576, B, C,
                  L, D_MODEL, D_MODEL, scale, As, Bs);
}

__global__ __launch_bounds__(256) void qkv_proj_bf16_kernel(
    const ushort* __restrict__ Qb, const ushort* __restrict__ Kb,
    const ushort* __restrict__ Vb,
    const ushort* __restrict__ Wb,
    const float* __restrict__ Bq, const float* __restrict__ Bk,
    const float* __restrict__ Bv,
    ushort* qo, ushort* ko, ushort* vo, int L)
{
    __shared__ short As[2 * 4096];
    __shared__ short Bs[2 * 4096];
    const int z = blockIdx.z;
    const ushort *X; const float* B; ushort* C;
    float scale = 1.0f;
    if (z == 0)      { X = Qb; B = Bq; C = qo; scale = 0.125f * 1.44269504088896f; }
    else if (z == 1) { X = Kb; B = Bk; C = ko; }
    else             { X = Vb; B = Bv; C = vo; }
    gemm_pipe<4, ushort>(X, Wb + (size_t)z * 1048576, B, C,
                         L, D_MODEL, D_MODEL, scale, As, Bs);
}

__global__ __launch_bounds__(512) void out_proj_kernel(
    const ushort* __restrict__ Xa, const ushort* __restrict__ Wb,
    const float* __restrict__ Bo, float* out, int L)
{
    __shared__ short As[2 * 4096];
    __shared__ short Bs[2 * 4096];
    gemm_pipe<8, float>(Xa, Wb + (size_t)3 * 1048576, Bo, out,
                        L, D_MODEL, D_MODEL, 1.0f, As, Bs);
}

// Flash attention — R5 version, UNCHANGED (clean attribution of GEMM delta).
__global__ __launch_bounds__(512) void attn_kernel(
    const ushort* __restrict__ Qw,
    const ushort* __restrict__ Kw,
    const ushort* __restrict__ Vw,
    ushort* __restrict__ Ow, int L)
{
    __shared__ short Ks[64 * 64];
    __shared__ short Vs[64 * 64];
    __shared__ short Ps[8][16 * 64];

    const int tid  = threadIdx.x;
    const int w    = tid >> 6;
    const int lane = tid & 63;
    const int quad = lane >> 4;
    const int l15  = lane & 15;
    const int h    = blockIdx.y;
    const int q0   = blockIdx.x * 128;

    const ushort* qp = Qw + (size_t)(q0 + w * 16 + l15) * D_MODEL + h * DH + quad * 8;
    bf16x8 qf0 = *(const bf16x8*)(qp);
    bf16x8 qf1 = *(const bf16x8*)(qp + 32);

    const int kkey = tid >> 3;
    const int kc8  = tid & 7;
    const int vkey = lane;
    const int vdh  = w * 8;

    const int krswz0 = ((quad    ) ^ (l15 & 7)) * 8;
    const int krswz1 = ((quad + 4) ^ (l15 & 7)) * 8;

    f32x4 o[4] = {};
    float m_run = -3e38f, l_run = 0.f;
    const float thr = 8.0f;   // defer-max threshold (exp2 domain)

    const ushort* kptr = Kw + (size_t)kkey * D_MODEL + h * DH + kc8 * 8;
    const ushort* vptr = Vw + (size_t)vkey * D_MODEL + h * DH + vdh;
    bf16x8 kreg = *(const bf16x8*)kptr;
    bf16x8 vreg = *(const bf16x8*)vptr;

    for (int key0 = 0; key0 < L; key0 += 64) {
        __syncthreads();
        *(bf16x8*)&Ks[kkey * 64 + ((kc8 ^ (kkey & 7)) * 8)] = kreg;
        #pragma unroll
        for (int i = 0; i < 8; ++i)
            Vs[(vdh + i) * 64 + (((vkey >> 3) ^ i) * 8) + (vkey & 7)] = vreg[i];
        __syncthreads();

        if (key0 + 64 < L) {
            kptr += (size_t)64 * D_MODEL;
            vptr += (size_t)64 * D_MODEL;
            kreg = *(const bf16x8*)kptr;
            vreg = *(const bf16x8*)vptr;
        }

        f32x4 st[4];
        __builtin_amdgcn_s_setprio(1);
        #pragma unroll
        for (int kt = 0; kt < 4; ++kt) {
            const int kr = (kt * 16 + l15) * 64;
            bf16x8 kf0 = *(const bf16x8*)&Ks[kr + krswz0];
            bf16x8 kf1 = *(const bf16x8*)&Ks[kr + krswz1];
            f32x4 z = {};
            z = __builtin_amdgcn_mfma_f32_16x16x32_bf16(kf0, qf0, z, 0, 0, 0);
            z = __builtin_amdgcn_mfma_f32_16x16x32_bf16(kf1, qf1, z, 0, 0, 0);
            st[kt] = z;
        }
        __builtin_amdgcn_s_setprio(0);

        float mx = st[0][0];
        #pragma unroll
        for (int kt = 0; kt < 4; ++kt)
            #pragma unroll
            for (int r = 0; r < 4; ++r)
                mx = fmaxf(mx, st[kt][r]);
        mx = fmaxf(mx, __shfl_xor(mx, 16));
        mx = fmaxf(mx, __shfl_xor(mx, 32));

        if (!__all(mx <= m_run + thr)) {
            const float mnew  = fmaxf(m_run, mx);
            const float alpha = __builtin_amdgcn_exp2f(m_run - mnew);
            m_run = mnew;
            l_run *= alpha;
            float a[4];
            #pragma unroll
            for (int r = 0; r < 4; ++r)
                a[r] = __shfl(alpha, (lane & 48) | (quad * 4 + r));
            #pragma unroll
            for (int dt = 0; dt < 4; ++dt)
                #pragma unroll
                for (int r = 0; r < 4; ++r)
                    o[dt][r] *= a[r];
        }

        float rs = 0.f;
        #pragma unroll
        for (int kt = 0; kt < 4; ++kt) {
            float p0 = __builtin_amdgcn_exp2f(st[kt][0] - m_run);
            float p1 = __builtin_amdgcn_exp2f(st[kt][1] - m_run);
            float p2 = __builtin_amdgcn_exp2f(st[kt][2] - m_run);
            float p3 = __builtin_amdgcn_exp2f(st[kt][3] - m_run);
            rs += (p0 + p1) + (p2 + p3);
            uint2 pk;
            pk.x = (uint32_t)f2bf(p0) | ((uint32_t)f2bf(p1) << 16);
            pk.y = (uint32_t)f2bf(p2) | ((uint32_t)f2bf(p3) << 16);
            const int G = kt * 2 + (quad >> 1);
            *(uint2*)&Ps[w][l15 * 64 + ((G ^ (l15 & 7)) * 8) + (quad & 1) * 4] = pk;
        }
        rs += __shfl_xor(rs, 16);
        rs += __shfl_xor(rs, 32);
        l_run += rs;

        __builtin_amdgcn_s_setprio(1);
        #pragma unroll
        for (int f = 0; f < 2; ++f) {
            bf16x8 pf = *(const bf16x8*)&Ps[w][l15 * 64 + (((f * 4 + quad) ^ (l15 & 7)) * 8)];
            #pragma unroll
            for (int dt = 0; dt < 4; ++dt) {
                bf16x8 vf = *(const bf16x8*)&Vs[(dt * 16 + l15) * 64 + (((f * 4 + quad) ^ (l15 & 7)) * 8)];
                o[dt] = __builtin_amdgcn_mfma_f32_16x16x32_bf16(pf, vf, o[dt], 0, 0, 0);
            }
        }
        __builtin_amdgcn_s_setprio(0);
    }

    const float inv = 1.f / l_run;
    #pragma unroll
    for (int r = 0; r < 4; ++r) {
        const float linv = __shfl(inv, (lane & 48) | (quad * 4 + r));
        const int row = q0 + w * 16 + quad * 4 + r;
        #pragma unroll
        for (int dt = 0; dt < 4; ++dt) {
            int col = h * DH + dt * 16 + l15;
            Ow[(size_t)row * D_MODEL + col] = (short)f2bf(o[dt][r] * linv);
        }
    }
}

extern "C" void kernel_launch(void* const* d_in, const int* in_sizes, int n_in,
                              void* d_out, int out_size, void* d_ws, size_t ws_size,
                              hipStream_t stream) {
    const float* Q   = (const float*)d_in[0];
    const float* K   = (const float*)d_in[1];
    const float* V   = (const float*)d_in[2];
    const float* w_q = (const float*)d_in[3];
    const float* b_q = (const float*)d_in[4];
    const float* w_k = (const float*)d_in[5];
    const float* b_k = (const float*)d_in[6];
    const float* w_v = (const float*)d_in[7];
    const float* b_v = (const float*)d_in[8];
    const float* w_o = (const float*)d_in[9];
    const float* b_o = (const float*)d_in[10];
    float* out = (float*)d_out;

    const int L = in_sizes[0] / D_MODEL;   // 4096
    const size_t mat = (size_t)L * D_MODEL;

    // Memory plan.
    // Fallback (ws >= 24 MB): d_ws [0,8): Wb | [8,16): a_ws | [16,24): v_ws;
    //   d_out [0,8): q_ws | [8,16): k_ws (dead before out_proj's fp32 C).
    // Extended (ws >= 40 MB, confirmed active in R5): one-shot bf16 X:
    //   d_ws [0,8): Wb | [8,16): Vb -> a_ws | [16,24): v_ws |
    //        [24,32): Qb | [32,40): Kb
    ushort* Wb   = (ushort*)d_ws;
    ushort* q_ws = (ushort*)d_out;
    ushort* k_ws = q_ws + mat;
    const bool ext = ws_size >= (size_t)40 * 1024 * 1024;

    ushort *a_ws, *v_ws, *Qb = nullptr, *Kb = nullptr, *Vb = nullptr;
    if (ext) {
        Vb   = (ushort*)d_ws + 4 * 1048576;   // [8,16)
        v_ws = Vb + mat;                      // [16,24)
        Qb   = v_ws + mat;                    // [24,32)
        Kb   = Qb + mat;                      // [32,40)
        a_ws = Vb;                            // reuse after qkv consumes Vb
    } else {
        a_ws = (ushort*)d_ws + 4 * 1048576;
        v_ws = a_ws + mat;
    }

    cvt_w_kernel<<<dim3(2048), dim3(256), 0, stream>>>(w_q, w_k, w_v, w_o, Wb);

    dim3 gqkv(D_MODEL / 128, L / 128, 3);
    if (ext) {
        cvt_x_kernel<<<dim3(2048, 1, 3), dim3(256), 0, stream>>>(Q, K, V, Qb, Kb, Vb);
        qkv_proj_bf16_kernel<<<gqkv, dim3(256), 0, stream>>>(Qb, Kb, Vb, Wb,
                                                             b_q, b_k, b_v,
                                                             q_ws, k_ws, v_ws, L);
    } else {
        qkv_proj_f32_kernel<<<gqkv, dim3(256), 0, stream>>>(Q, K, V, Wb,
                                                            b_q, b_k, b_v,
                                                            q_ws, k_ws, v_ws, L);
    }
    dim3 gattn(L / 128, NHEAD);
    attn_kernel<<<gattn, dim3(512), 0, stream>>>(q_ws, k_ws, v_ws, a_ws, L);
    dim3 gout(D_MODEL / 128, L / 128);
    out_proj_kernel<<<gout, dim3(512), 0, stream>>>(a_ws, Wb, b_o, out, L);
}